// Round 7
// baseline (172.900 us; speedup 1.0000x reference)
//
#include <hip/hip_runtime.h>

#define NSAMP 32
#define NELEM 307200                    // 480*640 per sample
#define LAM 0.5f
#define EPS 1e-6f
#define THREADS 256
#define F4_TOTAL (NSAMP * NELEM / 4)    // 2,457,600 float4
#define NBLOCKS 1920
#define F4_PER_BLOCK (F4_TOTAL / NBLOCKS)       // 1280 exactly
#define BLOCKS_PER_SAMPLE (NBLOCKS / NSAMP)     // 60 exactly

// ws float offsets — padded so no 128-B line sees more than ~60 device-scope
// RMWs (R3/R4 lesson: ~55 ns serialization PER CACHE LINE, not per address).
// Poison 0xAA = -3.03e-13f: negligible on accumulators; float counters still
// step through exact integers (+1.0 rounds the poison away).
#define PART_BASE 0                              // blk*8 + {0,1,2}: unique slots, 32 B apart
#define CNT_BASE  (NBLOCKS * 8)                  // + b*64: per-sample counters, 256 B apart
#define PS_BASE   (CNT_BASE + NSAMP * 64)        // + b*32: per-sample loss slots, 128 B apart
#define GCNT      (PS_BASE + NSAMP * 32)         // global completion counter

__device__ __forceinline__ void accum(float p, float t, float& s1, float& s2, float& c) {
    bool m = t > 0.f;
    float ld = __logf(p + EPS) - __logf(t + EPS);
    ld = m ? ld : 0.f;
    s1 += ld;
    s2 += ld * ld;
    c  += m ? 1.f : 0.f;
}

__global__ __launch_bounds__(THREADS, 4)
void sill_fused(const float* __restrict__ pred,
                const float* __restrict__ targ,
                float* __restrict__ ws,
                float* __restrict__ out) {
    const int blk = blockIdx.x;
    const int b   = blk / BLOCKS_PER_SAMPLE;
    const int tid = threadIdx.x;
    const size_t base = (size_t)blk * F4_PER_BLOCK;

    const float4* p4 = (const float4*)pred + base;
    const float4* t4 = (const float4*)targ + base;

    // 10 independent 16B loads issued before any use (R6's proven memory shape).
    float4 p0 = p4[tid];
    float4 p1 = p4[tid + 1 * THREADS];
    float4 p2 = p4[tid + 2 * THREADS];
    float4 p3 = p4[tid + 3 * THREADS];
    float4 pv = p4[tid + 4 * THREADS];
    float4 q0 = t4[tid];
    float4 q1 = t4[tid + 1 * THREADS];
    float4 q2 = t4[tid + 2 * THREADS];
    float4 q3 = t4[tid + 3 * THREADS];
    float4 qv = t4[tid + 4 * THREADS];

    float s1 = 0.f, s2 = 0.f, c = 0.f;
    accum(p0.x, q0.x, s1, s2, c); accum(p0.y, q0.y, s1, s2, c);
    accum(p0.z, q0.z, s1, s2, c); accum(p0.w, q0.w, s1, s2, c);
    accum(p1.x, q1.x, s1, s2, c); accum(p1.y, q1.y, s1, s2, c);
    accum(p1.z, q1.z, s1, s2, c); accum(p1.w, q1.w, s1, s2, c);
    accum(p2.x, q2.x, s1, s2, c); accum(p2.y, q2.y, s1, s2, c);
    accum(p2.z, q2.z, s1, s2, c); accum(p2.w, q2.w, s1, s2, c);
    accum(p3.x, q3.x, s1, s2, c); accum(p3.y, q3.y, s1, s2, c);
    accum(p3.z, q3.z, s1, s2, c); accum(p3.w, q3.w, s1, s2, c);
    accum(pv.x, qv.x, s1, s2, c); accum(pv.y, qv.y, s1, s2, c);
    accum(pv.z, qv.z, s1, s2, c); accum(pv.w, qv.w, s1, s2, c);

    // wave-64 reduction
    #pragma unroll
    for (int off = 32; off > 0; off >>= 1) {
        s1 += __shfl_down(s1, off);
        s2 += __shfl_down(s2, off);
        c  += __shfl_down(c,  off);
    }

    __shared__ float sh1[THREADS / 64];
    __shared__ float sh2[THREADS / 64];
    __shared__ float shc[THREADS / 64];
    const int wave = tid >> 6;
    if ((tid & 63) == 0) { sh1[wave] = s1; sh2[wave] = s2; shc[wave] = c; }
    __syncthreads();

    // ---- hierarchical completion tail, wave 0 only ----
    if (tid < 64) {
        float old = 0.f;
        if (tid == 0) {
            float a1 = 0.f, a2 = 0.f, ac = 0.f;
            #pragma unroll
            for (int w = 0; w < THREADS / 64; ++w) { a1 += sh1[w]; a2 += sh2[w]; ac += shc[w]; }
            atomicAdd(&ws[PART_BASE + blk * 8 + 0], a1);   // unique slot — no contention
            atomicAdd(&ws[PART_BASE + blk * 8 + 1], a2);
            atomicAdd(&ws[PART_BASE + blk * 8 + 2], ac);
            __threadfence();                               // release
            old = atomicAdd(&ws[CNT_BASE + b * 64], 1.0f); // 60 RMWs on a private line
        }
        old = __shfl(old, 0);
        if (old == (float)(BLOCKS_PER_SAMPLE - 1)) {
            __threadfence();                               // acquire
            float t1 = 0.f, t2 = 0.f, tc = 0.f;
            if (tid < BLOCKS_PER_SAMPLE) {
                int slot = PART_BASE + (b * BLOCKS_PER_SAMPLE + tid) * 8;
                t1 = atomicAdd(&ws[slot + 0], 0.0f);       // coherent fetch
                t2 = atomicAdd(&ws[slot + 1], 0.0f);
                tc = atomicAdd(&ws[slot + 2], 0.0f);
            }
            #pragma unroll
            for (int off = 32; off > 0; off >>= 1) {
                t1 += __shfl_down(t1, off);
                t2 += __shfl_down(t2, off);
                tc += __shfl_down(tc, off);
            }
            float old2 = 0.f;
            if (tid == 0) {
                float sc = fmaxf(tc, 1.f);
                float ml = t1 / sc;
                float ms = t2 / sc;
                float ps = ms - LAM * ml * ml;
                ps = (tc > 0.f) ? ps : 0.f;
                atomicAdd(&ws[PS_BASE + b * 32], ps);      // unique padded slot
                __threadfence();                           // release
                old2 = atomicAdd(&ws[GCNT], 1.0f);         // 32 RMWs on one line
            }
            old2 = __shfl(old2, 0);
            if (old2 == (float)(NSAMP - 1)) {
                __threadfence();                           // acquire
                float v = 0.f;
                if (tid < NSAMP) v = atomicAdd(&ws[PS_BASE + tid * 32], 0.0f);
                #pragma unroll
                for (int off = 32; off > 0; off >>= 1) v += __shfl_down(v, off);
                if (tid == 0) out[0] = v / (float)NSAMP;
            }
        }
    }
}

extern "C" void kernel_launch(void* const* d_in, const int* in_sizes, int n_in,
                              void* d_out, int out_size, void* d_ws, size_t ws_size,
                              hipStream_t stream) {
    const float* pred = (const float*)d_in[0];
    const float* targ = (const float*)d_in[1];
    float* out = (float*)d_out;
    float* ws  = (float*)d_ws;

    sill_fused<<<NBLOCKS, THREADS, 0, stream>>>(pred, targ, ws, out);
}